// Round 14
// baseline (197.705 us; speedup 1.0000x reference)
//
#include <hip/hip_runtime.h>
#include <hip/hip_bf16.h>
#include <cstdint>
#include <cstddef>

#define NN 4096

typedef float f32x4 __attribute__((ext_vector_type(4)));
typedef short s16x8 __attribute__((ext_vector_type(8)));

__device__ __forceinline__ float rdlane(float x, int lane) {
  return __int_as_float(__builtin_amdgcn_readlane(__float_as_int(x), lane));
}

// ---------- prep: bit-plane mask maskT[chunk][d] (bit i = row sbase+i); no atomics ----------
__global__ __launch_bounds__(256) void k_prep(const float* __restrict__ K,
                                              unsigned long long* __restrict__ maskT) {
  const int lane = threadIdx.x & 63;
  const int wv = threadIdx.x >> 6;
  const int d0 = blockIdx.x * 256 + lane * 4;      // each lane owns 4 columns
  const int sbase = blockIdx.y * 256 + wv * 64;    // this wave's 64-row chunk
  const int chunk = blockIdx.y * 4 + wv;
  unsigned long long w0 = 0, w1 = 0, w2 = 0, w3 = 0;
#pragma unroll 8
  for (int i = 0; i < 64; ++i) {
    const float4 kv = *(const float4*)(K + (size_t)(sbase + i) * NN + d0);
    w0 |= ((unsigned long long)(kv.x != 0.0f)) << i;
    w1 |= ((unsigned long long)(kv.y != 0.0f)) << i;
    w2 |= ((unsigned long long)(kv.z != 0.0f)) << i;
    w3 |= ((unsigned long long)(kv.w != 0.0f)) << i;
  }
  unsigned long long* mp = maskT + (size_t)chunk * NN + d0;
  mp[0] = w0; mp[1] = w1; mp[2] = w2; mp[3] = w3;
}

// ---------- register Sinkhorn, potentials form, 1 barrier/iter ----------
// Thread (w=tid>>6, l=tid&63) holds xR[j]=S0[l][jb+j]*20, xC[j]=S0[jb+j][l]*20 (jb=w*16).
// Every wave combines partials redundantly -> lane l of every wave holds the duals
// U[l], V[l] in registers at exit. pp = double-buffered partials (2*768 floats LDS).
// Called by all 256 threads; contains 20 barriers (first covers caller staging).
__device__ __forceinline__ void sinkhorn_reg(const float (&xR)[16], const float (&xC)[16],
    float& U, float& V, float* __restrict__ pp, int l, int w, int jb) {
  U = 0.f; V = 0.f;
#pragma unroll
  for (int it = 0; it < 20; ++it) {
    const bool row = (it & 1) == 0;
    float t[16];
#pragma unroll
    for (int j = 0; j < 16; ++j) {
      const float pot = rdlane(row ? V : U, jb + j);   // uniform idx, no LDS
      t[j] = (row ? xR[j] : xC[j]) - pot;
    }
    float a0 = fmaxf(t[0], t[1]),  a1 = fmaxf(t[2], t[3]);
    float a2 = fmaxf(t[4], t[5]),  a3 = fmaxf(t[6], t[7]);
    a0 = fmaxf(a0, fmaxf(t[8], t[9]));   a1 = fmaxf(a1, fmaxf(t[10], t[11]));
    a2 = fmaxf(a2, fmaxf(t[12], t[13])); a3 = fmaxf(a3, fmaxf(t[14], t[15]));
    const float mx = fmaxf(fmaxf(a0, a1), fmaxf(a2, a3));
    float s0 = 0.f, s1 = 0.f, s2 = 0.f, s3 = 0.f;
#pragma unroll
    for (int j = 0; j < 16; j += 4) {
      s0 += __expf(t[j] - mx);     s1 += __expf(t[j + 1] - mx);
      s2 += __expf(t[j + 2] - mx); s3 += __expf(t[j + 3] - mx);
    }
    const float sm = (s0 + s1) + (s2 + s3);
    float* buf = pp + (it & 1) * 768;
    buf[l * 12 + w] = mx;
    buf[l * 12 + 4 + w] = sm;
    __syncthreads();
    const f32x4 pm = *(const f32x4*)&buf[l * 12];     // all waves combine redundantly
    const f32x4 ps = *(const f32x4*)&buf[l * 12 + 4];
    const float mM = fmaxf(fmaxf(pm[0], pm[1]), fmaxf(pm[2], pm[3]));
    const float ss = ps[0] * __expf(pm[0] - mM) + ps[1] * __expf(pm[1] - mM)
                   + ps[2] * __expf(pm[2] - mM) + ps[3] * __expf(pm[3] - mM);
    const float lse = mM + __logf(ss);
    if (row) U = lse; else V = lse;
  }
}

// ---------- layer-0 transform: deg from maskT popcounts, disv, g hi/lo, xselfT ----------
__global__ __launch_bounds__(256) void k_xform0(const float* __restrict__ K,
    const unsigned long long* __restrict__ maskT,
    const float* __restrict__ cw, const float* __restrict__ cb,
    const float* __restrict__ sw, const float* __restrict__ sb,
    float* __restrict__ disv,
    __hip_bfloat16* __restrict__ gHi, __hip_bfloat16* __restrict__ gLo,
    float* __restrict__ xselfT) {
  __shared__ float pdeg[4][64];
  const int lane = threadIdx.x & 63;
  const int wv = threadIdx.x >> 6;
  const int s = blockIdx.x * 64 + lane;
  unsigned cnt = 0;
#pragma unroll
  for (int q = 0; q < 16; ++q)
    cnt += (unsigned)__popcll(maskT[(size_t)(wv * 16 + q) * NN + s]);
  pdeg[wv][lane] = (float)cnt;
  __syncthreads();
  const float ds = rsqrtf(pdeg[0][lane] + pdeg[1][lane] + pdeg[2][lane] + pdeg[3][lane]);
  if (wv == 0) disv[s] = ds;
  const float xv = K[(size_t)s * NN + s];          // diag(K)
#pragma unroll
  for (int i = 0; i < 16; ++i) {
    const int c = wv * 16 + i;
    const float gv = ds * xv * cw[c];
    const __hip_bfloat16 hi = __float2bfloat16(gv);
    gHi[(size_t)c * NN + s] = hi;
    gLo[(size_t)c * NN + s] = __float2bfloat16(gv - __bfloat162float(hi));
    xselfT[(size_t)c * NN + s] = xv * sw[c] + sb[c] + cb[c];
  }
}

// ---------- layer transform: reg sinkhorn + FMA + rank-1 sk fold ----------
// grid (64, 2): blockIdx.x = s-tile, blockIdx.y = 32-channel half. 256 threads.
__global__ __launch_bounds__(256, 1) void k_xform(const float* __restrict__ v,
    const float* __restrict__ vT,
    const float* __restrict__ xoutT, const float* __restrict__ disv,
    const float* __restrict__ cw, const float* __restrict__ cb,
    const float* __restrict__ sw, const float* __restrict__ sb,
    __hip_bfloat16* __restrict__ gHi, __hip_bfloat16* __restrict__ gLo,
    float* __restrict__ xselfT) {
  __shared__ __align__(16) float pp[2 * 768];
  __shared__ float xt[64][64];                     // raw xout
  __shared__ float wcl[64 * 32], wsl[64 * 32];     // [k][c-local]
  const int tid = threadIdx.x;
  const int l = tid & 63;
  const int w = tid >> 6;                          // 0..3
  const int jb = w * 16;
  const int s = blockIdx.x * 64 + l;
  const int cbase = blockIdx.y * 32;
  // ---- sinkhorn input into registers (tiny, L2-resident) ----
  float xR[16], xC[16];
#pragma unroll
  for (int q = 0; q < 4; ++q) {
    *(f32x4*)&xR[4 * q] = *(const f32x4*)&v[l * 64 + jb + 4 * q] * 20.0f;
    *(f32x4*)&xC[4 * q] = *(const f32x4*)&vT[l * 64 + jb + 4 * q] * 20.0f;
  }
  // ---- stage xt + weight slab (synced by sinkhorn's first barrier) ----
#pragma unroll
  for (int r = 0; r < 16; ++r)
    xt[w * 16 + r][l] = xoutT[(size_t)(w * 16 + r) * NN + s];
#pragma unroll
  for (int q = 0; q < 8; ++q) {
    const int e = w * 512 + q * 64 + l;            // e = k*32 + cl
    const int k = e >> 5, cl = e & 31;
    wcl[e] = cw[k * 64 + cbase + cl];
    wsl[e] = sw[k * 64 + cbase + cl];
  }
  float U, V;
  sinkhorn_reg(xR, xC, U, V, pp, l, w, jb);
  // ---- FMA: 8 channels per wave; float4 broadcast weight reads ----
  const int cl0 = w * 8;
  float accC[8], accS[8], csum[8], ssum[8];
#pragma unroll
  for (int i = 0; i < 8; ++i) { accC[i] = 0.f; accS[i] = 0.f; csum[i] = 0.f; ssum[i] = 0.f; }
  for (int k = 0; k < 64; ++k) {
    const float xv = xt[k][l];
    const f32x4 wcA = *(const f32x4*)&wcl[k * 32 + cl0];
    const f32x4 wcB = *(const f32x4*)&wcl[k * 32 + cl0 + 4];
    const f32x4 wsA = *(const f32x4*)&wsl[k * 32 + cl0];
    const f32x4 wsB = *(const f32x4*)&wsl[k * 32 + cl0 + 4];
#pragma unroll
    for (int i = 0; i < 4; ++i) {
      accC[i]     = fmaf(xv, wcA[i], accC[i]);     csum[i]     += wcA[i];
      accC[i + 4] = fmaf(xv, wcB[i], accC[i + 4]); csum[i + 4] += wcB[i];
      accS[i]     = fmaf(xv, wsA[i], accS[i]);     ssum[i]     += wsA[i];
      accS[i + 4] = fmaf(xv, wsB[i], accS[i + 4]); ssum[i + 4] += wsB[i];
    }
  }
  // ---- epilogue: sk from duals, rank-1 sk fold, bf16 hi/lo split ----
  const int bx = blockIdx.x;
  const float skv = __expf(20.0f * v[bx * 64 + l] - rdlane(U, bx) - V);
  const float ds = disv[s];
#pragma unroll
  for (int i = 0; i < 8; ++i) {
    const int c = cbase + cl0 + i;
    const float gv = ds * (accC[i] + skv * csum[i]);
    const __hip_bfloat16 hi = __float2bfloat16(gv);
    gHi[(size_t)c * NN + s] = hi;
    gLo[(size_t)c * NN + s] = __float2bfloat16(gv - __bfloat162float(hi));
    xselfT[(size_t)c * NN + s] = accS[i] + skv * ssum[i] + sb[c] + cb[c];
  }
}

// ---------- MFMA masked aggregation + in-block combine (+ final-score fold on last layer) ----------
__global__ __launch_bounds__(512) void k_agg(const unsigned long long* __restrict__ maskT,
    const __hip_bfloat16* __restrict__ gHi, const __hip_bfloat16* __restrict__ gLo,
    const float* __restrict__ xselfT, const float* __restrict__ disv,
    const float* __restrict__ kw, const float* __restrict__ kb,
    const float* __restrict__ fw, const float* __restrict__ fb,
    float* __restrict__ xoutT, float* __restrict__ v, float* __restrict__ vT,
    float* __restrict__ sbF) {
  const int tid = threadIdx.x;
  const int lane = tid & 63;
  const int wv = tid >> 6;           // 0..7
  const int mtile = wv & 3;          // channel 16-group
  const int ks = wv >> 2;            // K-split 0/1
  const int l15 = lane & 15;
  const int h = lane >> 4;           // 0..3
  const int d = blockIdx.x * 16 + l15;
  const int ch = mtile * 16 + l15;   // A-operand row (channel)
  const short* __restrict__ gh = (const short*)gHi;
  const short* __restrict__ gl = (const short*)gLo;
  f32x4 acch = {0.f, 0.f, 0.f, 0.f};
  f32x4 accl = {0.f, 0.f, 0.f, 0.f};
  const int c0 = ks * 32;
#pragma unroll 4
  for (int c = c0; c < c0 + 32; ++c) {
    const unsigned long long w = maskT[(size_t)c * NN + d];
    const unsigned half0 = (unsigned)w, half1 = (unsigned)(w >> 32);
#pragma unroll
    for (int t = 0; t < 2; ++t) {
      const unsigned half = t ? half1 : half0;
      const unsigned hb = (half >> (8 * h)) & 0xFFu;
      s16x8 bfr;
#pragma unroll
      for (int j = 0; j < 8; ++j)
        bfr[j] = (short)(((hb >> j) & 1u) * 0x3F80u);   // bit -> bf16 1.0/0.0
      const size_t abase = (size_t)ch * NN + (size_t)(c * 64 + t * 32 + 8 * h);
      const s16x8 ah = *(const s16x8*)(gh + abase);
      const s16x8 al = *(const s16x8*)(gl + abase);
      acch = __builtin_amdgcn_mfma_f32_16x16x32_bf16(ah, bfr, acch, 0, 0, 0);
      accl = __builtin_amdgcn_mfma_f32_16x16x32_bf16(al, bfr, accl, 0, 0, 0);
    }
  }
  __shared__ float rbuf[4][64][5];
  __shared__ float vred[16][17];
  __shared__ float vred2[16][17];
  f32x4 tot;
#pragma unroll
  for (int r = 0; r < 4; ++r) tot[r] = acch[r] + accl[r];
  if (ks == 1) {
#pragma unroll
    for (int r = 0; r < 4; ++r) rbuf[mtile][lane][r] = tot[r];
  }
  __syncthreads();
  if (ks == 0) {
    // C/D layout: col = lane&15 (=d), row = (lane>>4)*4 + reg (=channel in mtile)
    const float dd = disv[d];
    float p = 0.f, p2 = 0.f;
#pragma unroll
    for (int r = 0; r < 4; ++r) {
      const int chr = mtile * 16 + h * 4 + r;
      const float xo = xselfT[(size_t)chr * NN + d] + dd * (tot[r] + rbuf[mtile][lane][r]);
      xoutT[(size_t)chr * NN + d] = xo;
      p = fmaf(xo, kw[chr], p);
      p2 = fmaf(xo, fw[chr], p2);    // final-score partial (used only on last layer)
    }
    vred[l15][mtile * 4 + h] = p;
    vred2[l15][mtile * 4 + h] = p2;
  }
  __syncthreads();
  if (tid < 16) {
    float sum = kb[0];
#pragma unroll
    for (int q = 0; q < 16; ++q) sum += vred[tid][q];
    const int d2 = blockIdx.x * 16 + tid;
    v[d2] = sum;                                   // flat: row-major S0
    vT[(d2 & 63) * 64 + (d2 >> 6)] = sum;          // transposed
    if (sbF != nullptr) {                          // last layer: base scores, flat
      float sum2 = fb[0];
#pragma unroll
      for (int q = 0; q < 16; ++q) sum2 += vred2[tid][q];
      sbF[d2] = sum2;
    }
  }
}

// ---------- final: reg sinkhorn(sk2) -> fold (LDS orientation swap) -> reg sinkhorn -> out ----------
__global__ __launch_bounds__(256, 1) void k_final(const float* __restrict__ v,
    const float* __restrict__ vT, const float* __restrict__ sbF,
    const float* __restrict__ fw, float* __restrict__ out) {
  __shared__ __align__(16) float pp[2 * 768];
  __shared__ __align__(16) float scR[64 * 68];     // folded S row-major
  __shared__ __align__(16) float scT[64 * 68];     // folded S col-major
  __shared__ float fwl[64];
  const int tid = threadIdx.x;
  const int l = tid & 63;
  const int w = tid >> 6;
  const int jb = w * 16;
  float xR[16], xC[16];
#pragma unroll
  for (int q = 0; q < 4; ++q) {
    *(f32x4*)&xR[4 * q] = *(const f32x4*)&v[l * 64 + jb + 4 * q] * 20.0f;
    *(f32x4*)&xC[4 * q] = *(const f32x4*)&vT[l * 64 + jb + 4 * q] * 20.0f;
  }
  if (tid < 64) fwl[tid] = fw[tid];
  float U1, V1;
  sinkhorn_reg(xR, xC, U1, V1, pp, l, w, jb);      // sk2 duals
  float sumw = 0.f;
#pragma unroll
  for (int k = 0; k < 64; ++k) sumw += fwl[k];     // broadcast reads
  // ---- fold: S[i1=n&63][i2=n>>6] = (scores[n] + sk2[n]*sumw)*20 ----
#pragma unroll
  for (int k = 0; k < 16; ++k) {
    const int n = k * 256 + tid;                   // r2 = n>>6 uniform per iter
    const int r2 = 4 * k + w;
    const float sk2 = __expf(20.0f * v[n] - rdlane(U1, r2) - V1);
    const float val = (sbF[n] + sk2 * sumw) * 20.0f;
    scR[l * 68 + r2] = val;                        // S[i1=l][i2=r2]
    scT[r2 * 68 + l] = val;
  }
  __syncthreads();
  // ---- reload regs in both orientations (stride-68 b128: conflict-free) ----
#pragma unroll
  for (int q = 0; q < 4; ++q) {
    *(f32x4*)&xR[4 * q] = *(const f32x4*)&scR[l * 68 + jb + 4 * q];
    *(f32x4*)&xC[4 * q] = *(const f32x4*)&scT[l * 68 + jb + 4 * q];
  }
  float U2, V2;
  sinkhorn_reg(xR, xC, U2, V2, pp, l, w, jb);
  // ---- output: out[i1*64+i2] = exp(S - U[i1] - V[i2]) ----
#pragma unroll
  for (int q = 0; q < 16; ++q) {
    const int e = q * 256 + tid;                   // i1 = 4q+w (uniform), i2 = l
    const int i1 = 4 * q + w;
    out[e] = __expf(scR[i1 * 68 + l] - rdlane(U2, i1) - V2);
  }
}

extern "C" void kernel_launch(void* const* d_in, const int* in_sizes, int n_in,
                              void* d_out, int out_size, void* d_ws, size_t ws_size,
                              hipStream_t stream) {
  const float* K = (const float*)d_in[0];
  const float* cw[3] = {(const float*)d_in[4],  (const float*)d_in[10], (const float*)d_in[16]};
  const float* cb[3] = {(const float*)d_in[5],  (const float*)d_in[11], (const float*)d_in[17]};
  const float* sw[3] = {(const float*)d_in[6],  (const float*)d_in[12], (const float*)d_in[18]};
  const float* sb[3] = {(const float*)d_in[7],  (const float*)d_in[13], (const float*)d_in[19]};
  const float* kw[3] = {(const float*)d_in[8],  (const float*)d_in[14], (const float*)d_in[20]};
  const float* kb[3] = {(const float*)d_in[9],  (const float*)d_in[15], (const float*)d_in[21]};
  const float* fw = (const float*)d_in[22];
  const float* fb = (const float*)d_in[23];
  float* out = (float*)d_out;

  char* ws = (char*)d_ws;
  const size_t KB = 1024, MB = 1024 * 1024;
  float* disv               = (float*)(ws + 0);                   // 16 KB
  float* v                  = (float*)(ws + 16 * KB);             // 16 KB
  float* vT                 = (float*)(ws + 32 * KB);             // 16 KB
  float* sbF                = (float*)(ws + 48 * KB);             // 16 KB
  unsigned long long* maskT = (unsigned long long*)(ws + 64 * KB);// 2 MB
  __hip_bfloat16* gHi       = (__hip_bfloat16*)(ws + 64 * KB + 2 * MB);            // 512 KB
  __hip_bfloat16* gLo       = (__hip_bfloat16*)(ws + 64 * KB + 2 * MB + 512 * KB); // 512 KB
  float* xselfT             = (float*)(ws + 64 * KB + 3 * MB);    // 1 MB
  float* xoutT              = (float*)(ws + 64 * KB + 4 * MB);    // 1 MB
  (void)in_sizes; (void)n_in; (void)out_size; (void)ws_size;

  k_prep<<<dim3(16, 16), 256, 0, stream>>>(K, maskT);
  k_xform0<<<64, 256, 0, stream>>>(K, maskT, cw[0], cb[0], sw[0], sb[0],
                                   disv, gHi, gLo, xselfT);
  k_agg<<<256, 512, 0, stream>>>(maskT, gHi, gLo, xselfT, disv, kw[0], kb[0],
                                 fw, fb, xoutT, v, vT, nullptr);
  for (int l = 1; l < 3; ++l) {
    k_xform<<<dim3(64, 2), 256, 0, stream>>>(v, vT, xoutT, disv, cw[l], cb[l], sw[l], sb[l],
                                             gHi, gLo, xselfT);
    k_agg<<<256, 512, 0, stream>>>(maskT, gHi, gLo, xselfT, disv, kw[l], kb[l],
                                   fw, fb, xoutT, v, vT, (l == 2) ? sbF : nullptr);
  }
  k_final<<<1, 256, 0, stream>>>(v, vT, sbF, fw, out);
}

// Round 15
// 191.127 us; speedup vs baseline: 1.0344x; 1.0344x over previous
//
#include <hip/hip_runtime.h>
#include <hip/hip_bf16.h>
#include <cstdint>
#include <cstddef>

#define NN 4096

typedef float f32x4 __attribute__((ext_vector_type(4)));
typedef short s16x8 __attribute__((ext_vector_type(8)));

__device__ __forceinline__ float rdlane(float x, int lane) {
  return __int_as_float(__builtin_amdgcn_readlane(__float_as_int(x), lane));
}

// ---------- prep: bit-plane mask maskT[chunk][d] (bit i = row sbase+i); no atomics ----------
__global__ __launch_bounds__(256) void k_prep(const float* __restrict__ K,
                                              unsigned long long* __restrict__ maskT) {
  const int lane = threadIdx.x & 63;
  const int wv = threadIdx.x >> 6;
  const int d0 = blockIdx.x * 256 + lane * 4;      // each lane owns 4 columns
  const int sbase = blockIdx.y * 256 + wv * 64;    // this wave's 64-row chunk
  const int chunk = blockIdx.y * 4 + wv;
  unsigned long long w0 = 0, w1 = 0, w2 = 0, w3 = 0;
#pragma unroll 8
  for (int i = 0; i < 64; ++i) {
    const float4 kv = *(const float4*)(K + (size_t)(sbase + i) * NN + d0);
    w0 |= ((unsigned long long)(kv.x != 0.0f)) << i;
    w1 |= ((unsigned long long)(kv.y != 0.0f)) << i;
    w2 |= ((unsigned long long)(kv.z != 0.0f)) << i;
    w3 |= ((unsigned long long)(kv.w != 0.0f)) << i;
  }
  unsigned long long* mp = maskT + (size_t)chunk * NN + d0;
  mp[0] = w0; mp[1] = w1; mp[2] = w2; mp[3] = w3;
}

// ---------- register Sinkhorn (unrolled; for high-overlap contexts like k_xform) ----------
// Thread (w=tid>>6, l=tid&63) holds xR[j]=S0[l][jb+j]*20, xC[j]=S0[jb+j][l]*20 (jb=w*16).
// Every wave combines partials redundantly -> lane l of every wave holds U[l], V[l] at exit.
__device__ __forceinline__ void sinkhorn_reg(const float (&xR)[16], const float (&xC)[16],
    float& U, float& V, float* __restrict__ pp, int l, int w, int jb) {
  U = 0.f; V = 0.f;
#pragma unroll
  for (int it = 0; it < 20; ++it) {
    const bool row = (it & 1) == 0;
    float t[16];
#pragma unroll
    for (int j = 0; j < 16; ++j) {
      const float pot = rdlane(row ? V : U, jb + j);   // uniform idx, no LDS
      t[j] = (row ? xR[j] : xC[j]) - pot;
    }
    float a0 = fmaxf(t[0], t[1]),  a1 = fmaxf(t[2], t[3]);
    float a2 = fmaxf(t[4], t[5]),  a3 = fmaxf(t[6], t[7]);
    a0 = fmaxf(a0, fmaxf(t[8], t[9]));   a1 = fmaxf(a1, fmaxf(t[10], t[11]));
    a2 = fmaxf(a2, fmaxf(t[12], t[13])); a3 = fmaxf(a3, fmaxf(t[14], t[15]));
    const float mx = fmaxf(fmaxf(a0, a1), fmaxf(a2, a3));
    float s0 = 0.f, s1 = 0.f, s2 = 0.f, s3 = 0.f;
#pragma unroll
    for (int j = 0; j < 16; j += 4) {
      s0 += __expf(t[j] - mx);     s1 += __expf(t[j + 1] - mx);
      s2 += __expf(t[j + 2] - mx); s3 += __expf(t[j + 3] - mx);
    }
    const float sm = (s0 + s1) + (s2 + s3);
    float* buf = pp + (it & 1) * 768;
    buf[l * 12 + w] = mx;
    buf[l * 12 + 4 + w] = sm;
    __syncthreads();
    const f32x4 pm = *(const f32x4*)&buf[l * 12];     // all waves combine redundantly
    const f32x4 ps = *(const f32x4*)&buf[l * 12 + 4];
    const float mM = fmaxf(fmaxf(pm[0], pm[1]), fmaxf(pm[2], pm[3]));
    const float ss = ps[0] * __expf(pm[0] - mM) + ps[1] * __expf(pm[1] - mM)
                   + ps[2] * __expf(pm[2] - mM) + ps[3] * __expf(pm[3] - mM);
    const float lse = mM + __logf(ss);
    if (row) U = lse; else V = lse;
  }
}

// ---------- rolled-loop Sinkhorn for low-TLP single-block contexts (k_final) ----------
// No readlane, no waterfall risk: each wave keeps a PRIVATE pot copy in LDS (potW[w]),
// written by its own lanes, read back as uniform b128 broadcasts after lgkmcnt (same-wave).
// One block barrier per iteration (double-buffered stride-64 partials, 2-way = free).
// On exit: lane l of every wave holds U[l], V[l]; uW[w*68+l] = U[l] (fenced) for
// wave-uniform U lookups by the caller.
__device__ __forceinline__ void sinkhorn_lds2(const float (&xR)[16], const float (&xC)[16],
    float& U, float& V, float* __restrict__ pp /*2*512*/,
    float* __restrict__ potW /*4*68*/, float* __restrict__ uW /*4*68*/,
    int l, int w, int jb) {
  potW[w * 68 + l] = 0.0f;                         // V_0 = 0 (own wave's copy)
  asm volatile("s_waitcnt lgkmcnt(0)" ::: "memory");
  U = 0.f; V = 0.f;
#pragma unroll 1
  for (int it = 0; it < 20; ++it) {
    const bool row = (it & 1) == 0;
    const f32x4 p0 = *(const f32x4*)&potW[w * 68 + jb];       // uniform b128, own copy
    const f32x4 p1 = *(const f32x4*)&potW[w * 68 + jb + 4];
    const f32x4 p2 = *(const f32x4*)&potW[w * 68 + jb + 8];
    const f32x4 p3 = *(const f32x4*)&potW[w * 68 + jb + 12];
    f32x4 x0, x1, x2, x3;
    if (row) {
      x0 = *(const f32x4*)&xR[0];  x1 = *(const f32x4*)&xR[4];
      x2 = *(const f32x4*)&xR[8];  x3 = *(const f32x4*)&xR[12];
    } else {
      x0 = *(const f32x4*)&xC[0];  x1 = *(const f32x4*)&xC[4];
      x2 = *(const f32x4*)&xC[8];  x3 = *(const f32x4*)&xC[12];
    }
    x0 -= p0; x1 -= p1; x2 -= p2; x3 -= p3;
    f32x4 mA;
#pragma unroll
    for (int i = 0; i < 4; ++i)
      mA[i] = fmaxf(fmaxf(x0[i], x1[i]), fmaxf(x2[i], x3[i]));
    const float mx = fmaxf(fmaxf(mA[0], mA[1]), fmaxf(mA[2], mA[3]));
    float sm = 0.f;
#pragma unroll
    for (int i = 0; i < 4; ++i)
      sm += __expf(x0[i] - mx) + __expf(x1[i] - mx) +
            __expf(x2[i] - mx) + __expf(x3[i] - mx);
    float* buf = pp + (it & 1) * 512;
    buf[w * 64 + l] = mx;                          // stride-64: 2-way = free
    buf[256 + w * 64 + l] = sm;
    __syncthreads();
    const float m0 = buf[l],       m1 = buf[64 + l];
    const float m2 = buf[128 + l], m3 = buf[192 + l];
    const float q0 = buf[256 + l],       q1 = buf[320 + l];
    const float q2 = buf[384 + l],       q3 = buf[448 + l];
    const float mM = fmaxf(fmaxf(m0, m1), fmaxf(m2, m3));
    const float ss = q0 * __expf(m0 - mM) + q1 * __expf(m1 - mM)
                   + q2 * __expf(m2 - mM) + q3 * __expf(m3 - mM);
    const float lse = mM + __logf(ss);
    if (row) U = lse; else V = lse;
    potW[w * 68 + l] = lse;                        // own copy; next iter reads it
    asm volatile("s_waitcnt lgkmcnt(0)" ::: "memory");
  }
  uW[w * 68 + l] = U;                              // uniform-U lookup for caller
  asm volatile("s_waitcnt lgkmcnt(0)" ::: "memory");
}

// ---------- layer-0 transform: deg from maskT popcounts, disv, g hi/lo, xselfT ----------
__global__ __launch_bounds__(256) void k_xform0(const float* __restrict__ K,
    const unsigned long long* __restrict__ maskT,
    const float* __restrict__ cw, const float* __restrict__ cb,
    const float* __restrict__ sw, const float* __restrict__ sb,
    float* __restrict__ disv,
    __hip_bfloat16* __restrict__ gHi, __hip_bfloat16* __restrict__ gLo,
    float* __restrict__ xselfT) {
  __shared__ float pdeg[4][64];
  const int lane = threadIdx.x & 63;
  const int wv = threadIdx.x >> 6;
  const int s = blockIdx.x * 64 + lane;
  unsigned cnt = 0;
#pragma unroll
  for (int q = 0; q < 16; ++q)
    cnt += (unsigned)__popcll(maskT[(size_t)(wv * 16 + q) * NN + s]);
  pdeg[wv][lane] = (float)cnt;
  __syncthreads();
  const float ds = rsqrtf(pdeg[0][lane] + pdeg[1][lane] + pdeg[2][lane] + pdeg[3][lane]);
  if (wv == 0) disv[s] = ds;
  const float xv = K[(size_t)s * NN + s];          // diag(K)
#pragma unroll
  for (int i = 0; i < 16; ++i) {
    const int c = wv * 16 + i;
    const float gv = ds * xv * cw[c];
    const __hip_bfloat16 hi = __float2bfloat16(gv);
    gHi[(size_t)c * NN + s] = hi;
    gLo[(size_t)c * NN + s] = __float2bfloat16(gv - __bfloat162float(hi));
    xselfT[(size_t)c * NN + s] = xv * sw[c] + sb[c] + cb[c];
  }
}

// ---------- layer transform: reg sinkhorn + FMA + rank-1 sk fold (UNCHANGED, fast) ----------
// grid (64, 2): blockIdx.x = s-tile, blockIdx.y = 32-channel half. 256 threads.
__global__ __launch_bounds__(256, 1) void k_xform(const float* __restrict__ v,
    const float* __restrict__ vT,
    const float* __restrict__ xoutT, const float* __restrict__ disv,
    const float* __restrict__ cw, const float* __restrict__ cb,
    const float* __restrict__ sw, const float* __restrict__ sb,
    __hip_bfloat16* __restrict__ gHi, __hip_bfloat16* __restrict__ gLo,
    float* __restrict__ xselfT) {
  __shared__ __align__(16) float pp[2 * 768];
  __shared__ float xt[64][64];                     // raw xout
  __shared__ float wcl[64 * 32], wsl[64 * 32];     // [k][c-local]
  const int tid = threadIdx.x;
  const int l = tid & 63;
  const int w = tid >> 6;                          // 0..3
  const int jb = w * 16;
  const int s = blockIdx.x * 64 + l;
  const int cbase = blockIdx.y * 32;
  // ---- sinkhorn input into registers (tiny, L2-resident) ----
  float xR[16], xC[16];
#pragma unroll
  for (int q = 0; q < 4; ++q) {
    *(f32x4*)&xR[4 * q] = *(const f32x4*)&v[l * 64 + jb + 4 * q] * 20.0f;
    *(f32x4*)&xC[4 * q] = *(const f32x4*)&vT[l * 64 + jb + 4 * q] * 20.0f;
  }
  // ---- stage xt + weight slab (synced by sinkhorn's first barrier) ----
#pragma unroll
  for (int r = 0; r < 16; ++r)
    xt[w * 16 + r][l] = xoutT[(size_t)(w * 16 + r) * NN + s];
#pragma unroll
  for (int q = 0; q < 8; ++q) {
    const int e = w * 512 + q * 64 + l;            // e = k*32 + cl
    const int k = e >> 5, cl = e & 31;
    wcl[e] = cw[k * 64 + cbase + cl];
    wsl[e] = sw[k * 64 + cbase + cl];
  }
  float U, V;
  sinkhorn_reg(xR, xC, U, V, pp, l, w, jb);
  // ---- FMA: 8 channels per wave; float4 broadcast weight reads ----
  const int cl0 = w * 8;
  float accC[8], accS[8], csum[8], ssum[8];
#pragma unroll
  for (int i = 0; i < 8; ++i) { accC[i] = 0.f; accS[i] = 0.f; csum[i] = 0.f; ssum[i] = 0.f; }
  for (int k = 0; k < 64; ++k) {
    const float xv = xt[k][l];
    const f32x4 wcA = *(const f32x4*)&wcl[k * 32 + cl0];
    const f32x4 wcB = *(const f32x4*)&wcl[k * 32 + cl0 + 4];
    const f32x4 wsA = *(const f32x4*)&wsl[k * 32 + cl0];
    const f32x4 wsB = *(const f32x4*)&wsl[k * 32 + cl0 + 4];
#pragma unroll
    for (int i = 0; i < 4; ++i) {
      accC[i]     = fmaf(xv, wcA[i], accC[i]);     csum[i]     += wcA[i];
      accC[i + 4] = fmaf(xv, wcB[i], accC[i + 4]); csum[i + 4] += wcB[i];
      accS[i]     = fmaf(xv, wsA[i], accS[i]);     ssum[i]     += wsA[i];
      accS[i + 4] = fmaf(xv, wsB[i], accS[i + 4]); ssum[i + 4] += wsB[i];
    }
  }
  // ---- epilogue: sk from duals, rank-1 sk fold, bf16 hi/lo split ----
  const int bx = blockIdx.x;
  const float skv = __expf(20.0f * v[bx * 64 + l] - rdlane(U, bx) - V);
  const float ds = disv[s];
#pragma unroll
  for (int i = 0; i < 8; ++i) {
    const int c = cbase + cl0 + i;
    const float gv = ds * (accC[i] + skv * csum[i]);
    const __hip_bfloat16 hi = __float2bfloat16(gv);
    gHi[(size_t)c * NN + s] = hi;
    gLo[(size_t)c * NN + s] = __float2bfloat16(gv - __bfloat162float(hi));
    xselfT[(size_t)c * NN + s] = accS[i] + skv * ssum[i] + sb[c] + cb[c];
  }
}

// ---------- MFMA masked aggregation + in-block combine (+ final-score fold on last layer) ----------
__global__ __launch_bounds__(512) void k_agg(const unsigned long long* __restrict__ maskT,
    const __hip_bfloat16* __restrict__ gHi, const __hip_bfloat16* __restrict__ gLo,
    const float* __restrict__ xselfT, const float* __restrict__ disv,
    const float* __restrict__ kw, const float* __restrict__ kb,
    const float* __restrict__ fw, const float* __restrict__ fb,
    float* __restrict__ xoutT, float* __restrict__ v, float* __restrict__ vT,
    float* __restrict__ sbF) {
  const int tid = threadIdx.x;
  const int lane = tid & 63;
  const int wv = tid >> 6;           // 0..7
  const int mtile = wv & 3;          // channel 16-group
  const int ks = wv >> 2;            // K-split 0/1
  const int l15 = lane & 15;
  const int h = lane >> 4;           // 0..3
  const int d = blockIdx.x * 16 + l15;
  const int ch = mtile * 16 + l15;   // A-operand row (channel)
  const short* __restrict__ gh = (const short*)gHi;
  const short* __restrict__ gl = (const short*)gLo;
  f32x4 acch = {0.f, 0.f, 0.f, 0.f};
  f32x4 accl = {0.f, 0.f, 0.f, 0.f};
  const int c0 = ks * 32;
#pragma unroll 4
  for (int c = c0; c < c0 + 32; ++c) {
    const unsigned long long w = maskT[(size_t)c * NN + d];
    const unsigned half0 = (unsigned)w, half1 = (unsigned)(w >> 32);
#pragma unroll
    for (int t = 0; t < 2; ++t) {
      const unsigned half = t ? half1 : half0;
      const unsigned hb = (half >> (8 * h)) & 0xFFu;
      s16x8 bfr;
#pragma unroll
      for (int j = 0; j < 8; ++j)
        bfr[j] = (short)(((hb >> j) & 1u) * 0x3F80u);   // bit -> bf16 1.0/0.0
      const size_t abase = (size_t)ch * NN + (size_t)(c * 64 + t * 32 + 8 * h);
      const s16x8 ah = *(const s16x8*)(gh + abase);
      const s16x8 al = *(const s16x8*)(gl + abase);
      acch = __builtin_amdgcn_mfma_f32_16x16x32_bf16(ah, bfr, acch, 0, 0, 0);
      accl = __builtin_amdgcn_mfma_f32_16x16x32_bf16(al, bfr, accl, 0, 0, 0);
    }
  }
  __shared__ float rbuf[4][64][5];
  __shared__ float vred[16][17];
  __shared__ float vred2[16][17];
  f32x4 tot;
#pragma unroll
  for (int r = 0; r < 4; ++r) tot[r] = acch[r] + accl[r];
  if (ks == 1) {
#pragma unroll
    for (int r = 0; r < 4; ++r) rbuf[mtile][lane][r] = tot[r];
  }
  __syncthreads();
  if (ks == 0) {
    // C/D layout: col = lane&15 (=d), row = (lane>>4)*4 + reg (=channel in mtile)
    const float dd = disv[d];
    float p = 0.f, p2 = 0.f;
#pragma unroll
    for (int r = 0; r < 4; ++r) {
      const int chr = mtile * 16 + h * 4 + r;
      const float xo = xselfT[(size_t)chr * NN + d] + dd * (tot[r] + rbuf[mtile][lane][r]);
      xoutT[(size_t)chr * NN + d] = xo;
      p = fmaf(xo, kw[chr], p);
      p2 = fmaf(xo, fw[chr], p2);    // final-score partial (used only on last layer)
    }
    vred[l15][mtile * 4 + h] = p;
    vred2[l15][mtile * 4 + h] = p2;
  }
  __syncthreads();
  if (tid < 16) {
    float sum = kb[0];
#pragma unroll
    for (int q = 0; q < 16; ++q) sum += vred[tid][q];
    const int d2 = blockIdx.x * 16 + tid;
    v[d2] = sum;                                   // flat: row-major S0
    vT[(d2 & 63) * 64 + (d2 >> 6)] = sum;          // transposed
    if (sbF != nullptr) {                          // last layer: base scores, flat
      float sum2 = fb[0];
#pragma unroll
      for (int q = 0; q < 16; ++q) sum2 += vred2[tid][q];
      sbF[d2] = sum2;
    }
  }
}

// ---------- final: rolled sinkhorn(sk2) -> fold (LDS swap) -> rolled sinkhorn -> out ----------
__global__ __launch_bounds__(256, 1) void k_final(const float* __restrict__ v,
    const float* __restrict__ vT, const float* __restrict__ sbF,
    const float* __restrict__ fw, float* __restrict__ out) {
  __shared__ __align__(16) float pp[2 * 512];
  __shared__ __align__(16) float potW[4 * 68];
  __shared__ __align__(16) float uW[4 * 68];
  __shared__ __align__(16) float scR[64 * 68];     // folded S row-major
  __shared__ __align__(16) float scT[64 * 68];     // folded S col-major
  __shared__ float fwl[64];
  const int tid = threadIdx.x;
  const int l = tid & 63;
  const int w = tid >> 6;
  const int jb = w * 16;
  float xR[16], xC[16];
#pragma unroll
  for (int q = 0; q < 4; ++q) {
    *(f32x4*)&xR[4 * q] = *(const f32x4*)&v[l * 64 + jb + 4 * q] * 20.0f;
    *(f32x4*)&xC[4 * q] = *(const f32x4*)&vT[l * 64 + jb + 4 * q] * 20.0f;
  }
  if (tid < 64) fwl[tid] = fw[tid];
  float U1, V1;
  sinkhorn_lds2(xR, xC, U1, V1, pp, potW, uW, l, w, jb);   // sk2 duals; uW = U1 copies
  float sumw = 0.f;
#pragma unroll
  for (int k = 0; k < 64; ++k) sumw += fwl[k];     // broadcast reads
  // ---- fold: S[i1=n&63][i2=n>>6] = (scores[n] + sk2[n]*sumw)*20 ----
#pragma unroll
  for (int k = 0; k < 16; ++k) {
    const int n = k * 256 + tid;                   // r2 = n>>6 uniform per iter
    const int r2 = 4 * k + w;
    const float u1r2 = uW[w * 68 + r2];            // own wave's copy, uniform read
    const float sk2 = __expf(20.0f * v[n] - u1r2 - V1);
    const float val = (sbF[n] + sk2 * sumw) * 20.0f;
    scR[l * 68 + r2] = val;                        // S[i1=l][i2=r2]
    scT[r2 * 68 + l] = val;
  }
  __syncthreads();
  // ---- reload regs in both orientations (stride-68 b128: conflict-free) ----
#pragma unroll
  for (int q = 0; q < 4; ++q) {
    *(f32x4*)&xR[4 * q] = *(const f32x4*)&scR[l * 68 + jb + 4 * q];
    *(f32x4*)&xC[4 * q] = *(const f32x4*)&scT[l * 68 + jb + 4 * q];
  }
  float U2, V2;
  sinkhorn_lds2(xR, xC, U2, V2, pp, potW, uW, l, w, jb);   // uW = U2 copies
  // ---- output: out[i1*64+i2] = exp(S - U2[i1] - V2[i2]) ----
#pragma unroll
  for (int q = 0; q < 16; ++q) {
    const int e = q * 256 + tid;                   // i1 = 4q+w (uniform), i2 = l
    const int i1 = 4 * q + w;
    out[e] = __expf(scR[i1 * 68 + l] - uW[w * 68 + i1] - V2);
  }
}

extern "C" void kernel_launch(void* const* d_in, const int* in_sizes, int n_in,
                              void* d_out, int out_size, void* d_ws, size_t ws_size,
                              hipStream_t stream) {
  const float* K = (const float*)d_in[0];
  const float* cw[3] = {(const float*)d_in[4],  (const float*)d_in[10], (const float*)d_in[16]};
  const float* cb[3] = {(const float*)d_in[5],  (const float*)d_in[11], (const float*)d_in[17]};
  const float* sw[3] = {(const float*)d_in[6],  (const float*)d_in[12], (const float*)d_in[18]};
  const float* sb[3] = {(const float*)d_in[7],  (const float*)d_in[13], (const float*)d_in[19]};
  const float* kw[3] = {(const float*)d_in[8],  (const float*)d_in[14], (const float*)d_in[20]};
  const float* kb[3] = {(const float*)d_in[9],  (const float*)d_in[15], (const float*)d_in[21]};
  const float* fw = (const float*)d_in[22];
  const float* fb = (const float*)d_in[23];
  float* out = (float*)d_out;

  char* ws = (char*)d_ws;
  const size_t KB = 1024, MB = 1024 * 1024;
  float* disv               = (float*)(ws + 0);                   // 16 KB
  float* v                  = (float*)(ws + 16 * KB);             // 16 KB
  float* vT                 = (float*)(ws + 32 * KB);             // 16 KB
  float* sbF                = (float*)(ws + 48 * KB);             // 16 KB
  unsigned long long* maskT = (unsigned long long*)(ws + 64 * KB);// 2 MB
  __hip_bfloat16* gHi       = (__hip_bfloat16*)(ws + 64 * KB + 2 * MB);            // 512 KB
  __hip_bfloat16* gLo       = (__hip_bfloat16*)(ws + 64 * KB + 2 * MB + 512 * KB); // 512 KB
  float* xselfT             = (float*)(ws + 64 * KB + 3 * MB);    // 1 MB
  float* xoutT              = (float*)(ws + 64 * KB + 4 * MB);    // 1 MB
  (void)in_sizes; (void)n_in; (void)out_size; (void)ws_size;

  k_prep<<<dim3(16, 16), 256, 0, stream>>>(K, maskT);
  k_xform0<<<64, 256, 0, stream>>>(K, maskT, cw[0], cb[0], sw[0], sb[0],
                                   disv, gHi, gLo, xselfT);
  k_agg<<<256, 512, 0, stream>>>(maskT, gHi, gLo, xselfT, disv, kw[0], kb[0],
                                 fw, fb, xoutT, v, vT, nullptr);
  for (int l = 1; l < 3; ++l) {
    k_xform<<<dim3(64, 2), 256, 0, stream>>>(v, vT, xoutT, disv, cw[l], cb[l], sw[l], sb[l],
                                             gHi, gLo, xselfT);
    k_agg<<<256, 512, 0, stream>>>(maskT, gHi, gLo, xselfT, disv, kw[l], kb[l],
                                   fw, fb, xoutT, v, vT, (l == 2) ? sbF : nullptr);
  }
  k_final<<<1, 256, 0, stream>>>(v, vT, sbF, fw, out);
}